// Round 1
// baseline (758.101 us; speedup 1.0000x reference)
//
#include <hip/hip_runtime.h>
#include <math.h>

// ---------------------------------------------------------------------------
// GAT 3-layer forward.  N=50000 nodes, E=800000 edges.
// Strategy: build CSR by dst once (reused across layers), then per layer:
//   GEMM (fp32 tiled)  ->  attn coeffs el/er  ->  per-node softmax+aggregate.
// ---------------------------------------------------------------------------

// ---------------- CSR build ----------------
__global__ void count_edges(const int* __restrict__ dst, int* __restrict__ cnt, int E) {
    int i = blockIdx.x * blockDim.x + threadIdx.x;
    if (i < E) atomicAdd(&cnt[dst[i]], 1);
}

__global__ void scan_block(const int* __restrict__ cnt, int* __restrict__ incl,
                           int* __restrict__ bsum, int n) {
    __shared__ int sh[256];
    int tid = threadIdx.x;
    int i = blockIdx.x * 256 + tid;
    int v = (i < n) ? cnt[i] : 0;
    sh[tid] = v;
    __syncthreads();
    for (int o = 1; o < 256; o <<= 1) {
        int t = (tid >= o) ? sh[tid - o] : 0;
        __syncthreads();
        sh[tid] += t;
        __syncthreads();
    }
    if (i < n) incl[i] = sh[tid];
    if (tid == 255) bsum[blockIdx.x] = sh[255];
}

__global__ void scan_sums(int* __restrict__ bsum, int g) {
    __shared__ int sh[256];
    int tid = threadIdx.x;
    int v = (tid < g) ? bsum[tid] : 0;
    sh[tid] = v;
    __syncthreads();
    for (int o = 1; o < 256; o <<= 1) {
        int t = (tid >= o) ? sh[tid - o] : 0;
        __syncthreads();
        sh[tid] += t;
        __syncthreads();
    }
    if (tid < g) bsum[tid] = sh[tid] - v;   // exclusive
}

__global__ void finalize_rowptr(const int* __restrict__ incl, const int* __restrict__ cnt,
                                const int* __restrict__ bsum, int* __restrict__ row_ptr,
                                int* __restrict__ nxt, int n, int E) {
    int i = blockIdx.x * 256 + threadIdx.x;
    if (i < n) {
        int v = incl[i] - cnt[i] + bsum[blockIdx.x];
        row_ptr[i] = v;
        nxt[i] = v;
    }
    if (i == 0) row_ptr[n] = E;
}

__global__ void fill_csr(const int* __restrict__ src, const int* __restrict__ dst,
                         int* __restrict__ nxt, int* __restrict__ csr_src, int E) {
    int i = blockIdx.x * blockDim.x + threadIdx.x;
    if (i < E) {
        int p = atomicAdd(&nxt[dst[i]], 1);
        csr_src[p] = src[i];
    }
}

// ---------------- fp32 tiled GEMM: C[N,M] = A[N,K] @ B[K,M] ----------------
#define BM 64
#define BN 64
#define BK 32

__global__ __launch_bounds__(256)
void gemm_tiled(const float* __restrict__ A, const float* __restrict__ B,
                float* __restrict__ C, int N, int K, int M) {
    __shared__ float As[BK][BM + 4];   // transposed A tile
    __shared__ float Bs[BK][BN + 4];
    int tid = threadIdx.x;
    int bm = blockIdx.y * BM;
    int bn = blockIdx.x * BN;
    int tn = (tid & 15) * 4;
    int tm = (tid >> 4) * 4;
    float acc[4][4] = {};
    for (int k0 = 0; k0 < K; k0 += BK) {
        // A tile 64x32, store transposed
        #pragma unroll
        for (int it = 0; it < 2; ++it) {
            int f = it * 256 + tid;      // float4 slot
            int r = f >> 3;              // 0..63
            int c = (f & 7) * 4;         // 0..28
            float4 v = make_float4(0.f, 0.f, 0.f, 0.f);
            int gr = bm + r;
            if (gr < N) v = *reinterpret_cast<const float4*>(&A[(size_t)gr * K + k0 + c]);
            As[c + 0][r] = v.x; As[c + 1][r] = v.y; As[c + 2][r] = v.z; As[c + 3][r] = v.w;
        }
        // B tile 32x64
        #pragma unroll
        for (int it = 0; it < 2; ++it) {
            int f = it * 256 + tid;
            int r = f >> 4;              // 0..31
            int c = (f & 15) * 4;        // 0..60
            float4 v = *reinterpret_cast<const float4*>(&B[(size_t)(k0 + r) * M + bn + c]);
            *reinterpret_cast<float4*>(&Bs[r][c]) = v;
        }
        __syncthreads();
        #pragma unroll
        for (int k = 0; k < BK; ++k) {
            float4 a = *reinterpret_cast<const float4*>(&As[k][tm]);
            float4 b = *reinterpret_cast<const float4*>(&Bs[k][tn]);
            acc[0][0] += a.x * b.x; acc[0][1] += a.x * b.y; acc[0][2] += a.x * b.z; acc[0][3] += a.x * b.w;
            acc[1][0] += a.y * b.x; acc[1][1] += a.y * b.y; acc[1][2] += a.y * b.z; acc[1][3] += a.y * b.w;
            acc[2][0] += a.z * b.x; acc[2][1] += a.z * b.y; acc[2][2] += a.z * b.z; acc[2][3] += a.z * b.w;
            acc[3][0] += a.w * b.x; acc[3][1] += a.w * b.y; acc[3][2] += a.w * b.z; acc[3][3] += a.w * b.w;
        }
        __syncthreads();
    }
    #pragma unroll
    for (int i = 0; i < 4; ++i) {
        int gm = bm + tm + i;
        if (gm < N) {
            float4 v = make_float4(acc[i][0], acc[i][1], acc[i][2], acc[i][3]);
            *reinterpret_cast<float4*>(&C[(size_t)gm * M + bn + tn]) = v;
        }
    }
}

// ---------------- attention coefficients el/er for H=4, D=64 ----------------
__global__ __launch_bounds__(256)
void attn_lr(const float* __restrict__ h, const float* __restrict__ al,
             const float* __restrict__ ar, float* __restrict__ el,
             float* __restrict__ er, int NH) {   // NH = N*4
    int gt = blockIdx.x * 256 + threadIdx.x;
    int w = gt >> 6;
    int lane = threadIdx.x & 63;
    if (w >= NH) return;
    int hd = w & 3;
    float v = h[(size_t)w * 64 + lane];
    float l = v * al[hd * 64 + lane];
    float r = v * ar[hd * 64 + lane];
    #pragma unroll
    for (int o = 32; o; o >>= 1) { l += __shfl_down(l, o); r += __shfl_down(r, o); }
    if (lane == 0) { el[w] = l; er[w] = r; }
}

// ---------------- softmax + aggregate, H=4, D=64 (256 cols) ----------------
__global__ __launch_bounds__(256)
void gat_agg(const float* __restrict__ h, const float* __restrict__ el,
             const float* __restrict__ er, const int* __restrict__ row_ptr,
             const int* __restrict__ csr_src, const float* __restrict__ bias,
             float* __restrict__ out, int N, int do_elu) {
    int n = blockIdx.x;
    int tid = threadIdx.x;
    int beg = row_ptr[n], end = row_ptr[n + 1];
    __shared__ float er_n[4], m_sh[4], s_sh[4];
    __shared__ int   src_ch[64];
    __shared__ float a_ch[64][4];
    if (tid < 4) er_n[tid] = er[n * 4 + tid];
    __syncthreads();
    if (tid < 64) {   // wave 0 computes softmax stats
        float mx0 = -INFINITY, mx1 = -INFINITY, mx2 = -INFINITY, mx3 = -INFINITY;
        for (int j = beg + tid; j < end; j += 64) {
            int s = csr_src[j];
            float e0 = el[s * 4 + 0] + er_n[0]; e0 = e0 > 0.f ? e0 : 0.2f * e0;
            float e1 = el[s * 4 + 1] + er_n[1]; e1 = e1 > 0.f ? e1 : 0.2f * e1;
            float e2 = el[s * 4 + 2] + er_n[2]; e2 = e2 > 0.f ? e2 : 0.2f * e2;
            float e3 = el[s * 4 + 3] + er_n[3]; e3 = e3 > 0.f ? e3 : 0.2f * e3;
            mx0 = fmaxf(mx0, e0); mx1 = fmaxf(mx1, e1); mx2 = fmaxf(mx2, e2); mx3 = fmaxf(mx3, e3);
        }
        #pragma unroll
        for (int o = 1; o < 64; o <<= 1) {
            mx0 = fmaxf(mx0, __shfl_xor(mx0, o));
            mx1 = fmaxf(mx1, __shfl_xor(mx1, o));
            mx2 = fmaxf(mx2, __shfl_xor(mx2, o));
            mx3 = fmaxf(mx3, __shfl_xor(mx3, o));
        }
        float s0 = 0.f, s1 = 0.f, s2 = 0.f, s3 = 0.f;
        for (int j = beg + tid; j < end; j += 64) {
            int s = csr_src[j];
            float e0 = el[s * 4 + 0] + er_n[0]; e0 = e0 > 0.f ? e0 : 0.2f * e0;
            float e1 = el[s * 4 + 1] + er_n[1]; e1 = e1 > 0.f ? e1 : 0.2f * e1;
            float e2 = el[s * 4 + 2] + er_n[2]; e2 = e2 > 0.f ? e2 : 0.2f * e2;
            float e3 = el[s * 4 + 3] + er_n[3]; e3 = e3 > 0.f ? e3 : 0.2f * e3;
            s0 += __expf(e0 - mx0); s1 += __expf(e1 - mx1);
            s2 += __expf(e2 - mx2); s3 += __expf(e3 - mx3);
        }
        #pragma unroll
        for (int o = 1; o < 64; o <<= 1) {
            s0 += __shfl_xor(s0, o); s1 += __shfl_xor(s1, o);
            s2 += __shfl_xor(s2, o); s3 += __shfl_xor(s3, o);
        }
        if (tid == 0) {
            m_sh[0] = mx0; m_sh[1] = mx1; m_sh[2] = mx2; m_sh[3] = mx3;
            s_sh[0] = s0;  s_sh[1] = s1;  s_sh[2] = s2;  s_sh[3] = s3;
        }
    }
    __syncthreads();
    int c = tid;
    int hd = tid >> 6;
    float sv = s_sh[hd];
    float inv_s = sv > 0.f ? 1.0f / sv : 0.0f;
    float acc = 0.f;
    for (int j0 = beg; j0 < end; j0 += 64) {
        int cnt = min(64, end - j0);
        __syncthreads();
        if (tid < cnt) {
            int s = csr_src[j0 + tid];
            src_ch[tid] = s;
            #pragma unroll
            for (int q = 0; q < 4; ++q) {
                float e = el[s * 4 + q] + er_n[q];
                e = e > 0.f ? e : 0.2f * e;
                a_ch[tid][q] = __expf(e - m_sh[q]);
            }
        }
        __syncthreads();
        int e2 = 0;
        for (; e2 + 4 <= cnt; e2 += 4) {
            float h0 = h[(size_t)src_ch[e2 + 0] * 256 + c];
            float h1 = h[(size_t)src_ch[e2 + 1] * 256 + c];
            float h2 = h[(size_t)src_ch[e2 + 2] * 256 + c];
            float h3 = h[(size_t)src_ch[e2 + 3] * 256 + c];
            acc += h0 * a_ch[e2 + 0][hd] + h1 * a_ch[e2 + 1][hd]
                 + h2 * a_ch[e2 + 2][hd] + h3 * a_ch[e2 + 3][hd];
        }
        for (; e2 < cnt; ++e2)
            acc += h[(size_t)src_ch[e2] * 256 + c] * a_ch[e2][hd];
    }
    acc *= inv_s;
    float v = acc + bias[c];
    if (do_elu) v = v > 0.f ? v : (__expf(v) - 1.0f);
    out[(size_t)n * 256 + c] = v;
}

// ---------------- layer 3: GEMM [N,256]x[256,8] + attn coeffs --------------
__global__ __launch_bounds__(256)
void gemm3_attn(const float* __restrict__ x, const float* __restrict__ W,
                const float* __restrict__ al, const float* __restrict__ ar,
                float* __restrict__ h3, float* __restrict__ el,
                float* __restrict__ er, int N) {
    __shared__ float Ws[256][9];
    int tid = threadIdx.x;
    #pragma unroll
    for (int d = 0; d < 8; ++d) Ws[tid][d] = W[tid * 8 + d];
    __syncthreads();
    int lane = tid & 63;
    int n = blockIdx.x * 4 + (tid >> 6);
    if (n >= N) return;
    float acc[8] = {};
    #pragma unroll
    for (int i = 0; i < 4; ++i) {
        int k = i * 64 + lane;
        float xv = x[(size_t)n * 256 + k];
        #pragma unroll
        for (int d = 0; d < 8; ++d) acc[d] += xv * Ws[k][d];
    }
    #pragma unroll
    for (int d = 0; d < 8; ++d) {
        #pragma unroll
        for (int o = 32; o; o >>= 1) acc[d] += __shfl_down(acc[d], o);
    }
    if (lane == 0) {
        float l = 0.f, r = 0.f;
        #pragma unroll
        for (int d = 0; d < 8; ++d) {
            h3[n * 8 + d] = acc[d];
            l += acc[d] * al[d];
            r += acc[d] * ar[d];
        }
        el[n] = l;
        er[n] = r;
    }
}

// ---------------- layer 3 softmax + aggregate (H=1, D=8) -------------------
__global__ __launch_bounds__(256)
void gat_agg3(const float* __restrict__ h3, const float* __restrict__ el,
              const float* __restrict__ er, const int* __restrict__ row_ptr,
              const int* __restrict__ csr_src, const float* __restrict__ bias,
              float* __restrict__ out, int N) {
    int tid = threadIdx.x;
    int lane = tid & 63;
    int n = blockIdx.x * 4 + (tid >> 6);
    if (n >= N) return;
    int beg = row_ptr[n], end = row_ptr[n + 1];
    float er_n = er[n];
    float mx = -INFINITY;
    for (int j = beg + lane; j < end; j += 64) {
        float e = el[csr_src[j]] + er_n; e = e > 0.f ? e : 0.2f * e;
        mx = fmaxf(mx, e);
    }
    #pragma unroll
    for (int o = 1; o < 64; o <<= 1) mx = fmaxf(mx, __shfl_xor(mx, o));
    float sm = 0.f;
    for (int j = beg + lane; j < end; j += 64) {
        float e = el[csr_src[j]] + er_n; e = e > 0.f ? e : 0.2f * e;
        sm += __expf(e - mx);
    }
    #pragma unroll
    for (int o = 1; o < 64; o <<= 1) sm += __shfl_xor(sm, o);
    float inv = sm > 0.f ? 1.0f / sm : 0.0f;
    int g = lane >> 3, c = lane & 7;
    float acc = 0.f;
    for (int j = beg + g; j < end; j += 8) {
        int s = csr_src[j];
        float e = el[s] + er_n; e = e > 0.f ? e : 0.2f * e;
        float a = __expf(e - mx) * inv;
        acc += h3[s * 8 + c] * a;
    }
    acc += __shfl_xor(acc, 8);
    acc += __shfl_xor(acc, 16);
    acc += __shfl_xor(acc, 32);
    if (lane < 8) out[(size_t)n * 8 + lane] = acc + bias[lane];
}

// ---------------------------------------------------------------------------
static inline size_t align_up(size_t x, size_t a) { return (x + a - 1) & ~(a - 1); }

extern "C" void kernel_launch(void* const* d_in, const int* in_sizes, int n_in,
                              void* d_out, int out_size, void* d_ws, size_t ws_size,
                              hipStream_t stream) {
    const float* feat = (const float*)d_in[0];
    const int*   src  = (const int*)d_in[1];
    const int*   dst  = (const int*)d_in[2];
    const float* W1   = (const float*)d_in[3];
    const float* al1  = (const float*)d_in[4];
    const float* ar1  = (const float*)d_in[5];
    const float* b1   = (const float*)d_in[6];
    const float* W2   = (const float*)d_in[7];
    const float* al2  = (const float*)d_in[8];
    const float* ar2  = (const float*)d_in[9];
    const float* b2   = (const float*)d_in[10];
    const float* W3   = (const float*)d_in[11];
    const float* al3  = (const float*)d_in[12];
    const float* ar3  = (const float*)d_in[13];
    const float* b3   = (const float*)d_in[14];

    const int N = in_sizes[0] / 128;
    const int E = in_sizes[1];

    char* w = (char*)d_ws;
    float* bufA    = (float*)w; w += align_up((size_t)N * 256 * 4, 256);
    float* bufB    = (float*)w; w += align_up((size_t)N * 256 * 4, 256);
    float* el      = (float*)w; w += align_up((size_t)N * 4 * 4, 256);
    float* er      = (float*)w; w += align_up((size_t)N * 4 * 4, 256);
    float* h3      = (float*)w; w += align_up((size_t)N * 8 * 4, 256);
    int*   cnt     = (int*)w;   w += align_up((size_t)N * 4, 256);
    int*   incl    = (int*)w;   w += align_up((size_t)N * 4, 256);
    int*   bsum    = (int*)w;   w += align_up(256 * 4, 256);
    int*   row_ptr = (int*)w;   w += align_up(((size_t)N + 1) * 4, 256);
    int*   nxt     = (int*)w;   w += align_up((size_t)N * 4, 256);
    int*   csr_src = (int*)w;   w += align_up((size_t)E * 4, 256);
    (void)ws_size; (void)n_in; (void)out_size;

    const int G1 = (N + 255) / 256;          // scan blocks (<=256 required)
    const int GE = (E + 255) / 256;

    // ---- CSR build (dst is identical for all layers) ----
    hipMemsetAsync(cnt, 0, (size_t)N * 4, stream);
    count_edges<<<GE, 256, 0, stream>>>(dst, cnt, E);
    scan_block<<<G1, 256, 0, stream>>>(cnt, incl, bsum, N);
    scan_sums<<<1, 256, 0, stream>>>(bsum, G1);
    finalize_rowptr<<<G1, 256, 0, stream>>>(incl, cnt, bsum, row_ptr, nxt, N, E);
    fill_csr<<<GE, 256, 0, stream>>>(src, dst, nxt, csr_src, E);

    dim3 ggrid(256 / BN, (N + BM - 1) / BM);

    // ---- layer 1 ----
    gemm_tiled<<<ggrid, 256, 0, stream>>>(feat, W1, bufA, N, 128, 256);
    attn_lr<<<(N * 4 * 64 + 255) / 256, 256, 0, stream>>>(bufA, al1, ar1, el, er, N * 4);
    gat_agg<<<N, 256, 0, stream>>>(bufA, el, er, row_ptr, csr_src, b1, bufB, N, 1);

    // ---- layer 2 ----
    gemm_tiled<<<ggrid, 256, 0, stream>>>(bufB, W2, bufA, N, 256, 256);
    attn_lr<<<(N * 4 * 64 + 255) / 256, 256, 0, stream>>>(bufA, al2, ar2, el, er, N * 4);
    gat_agg<<<N, 256, 0, stream>>>(bufA, el, er, row_ptr, csr_src, b2, bufB, N, 1);

    // ---- layer 3 ----
    gemm3_attn<<<(N + 3) / 4, 256, 0, stream>>>(bufB, W3, al3, ar3, h3, el, er, N);
    gat_agg3<<<(N + 3) / 4, 256, 0, stream>>>(h3, el, er, row_ptr, csr_src, b3,
                                              (float*)d_out, N);
}

// Round 2
// 592.819 us; speedup vs baseline: 1.2788x; 1.2788x over previous
//
#include <hip/hip_runtime.h>
#include <math.h>

// ---------------------------------------------------------------------------
// GAT 3-layer forward.  N=50000 nodes, E=800000 edges.
// Round 2: fp16 activations (fp32 accumulation), MFMA GEMMs, fp16 gather.
// ---------------------------------------------------------------------------

typedef _Float16 half8 __attribute__((ext_vector_type(8)));
typedef _Float16 half4 __attribute__((ext_vector_type(4)));
typedef float    floatx4 __attribute__((ext_vector_type(4)));

// ---------------- CSR build ----------------
__global__ void count_edges(const int* __restrict__ dst, int* __restrict__ cnt, int E) {
    int i = blockIdx.x * blockDim.x + threadIdx.x;
    if (i < E) atomicAdd(&cnt[dst[i]], 1);
}

__global__ void scan_block(const int* __restrict__ cnt, int* __restrict__ incl,
                           int* __restrict__ bsum, int n) {
    __shared__ int sh[256];
    int tid = threadIdx.x;
    int i = blockIdx.x * 256 + tid;
    int v = (i < n) ? cnt[i] : 0;
    sh[tid] = v;
    __syncthreads();
    for (int o = 1; o < 256; o <<= 1) {
        int t = (tid >= o) ? sh[tid - o] : 0;
        __syncthreads();
        sh[tid] += t;
        __syncthreads();
    }
    if (i < n) incl[i] = sh[tid];
    if (tid == 255) bsum[blockIdx.x] = sh[255];
}

__global__ void scan_sums(int* __restrict__ bsum, int g) {
    __shared__ int sh[256];
    int tid = threadIdx.x;
    int v = (tid < g) ? bsum[tid] : 0;
    sh[tid] = v;
    __syncthreads();
    for (int o = 1; o < 256; o <<= 1) {
        int t = (tid >= o) ? sh[tid - o] : 0;
        __syncthreads();
        sh[tid] += t;
        __syncthreads();
    }
    if (tid < g) bsum[tid] = sh[tid] - v;   // exclusive
}

__global__ void finalize_rowptr(const int* __restrict__ incl, const int* __restrict__ cnt,
                                const int* __restrict__ bsum, int* __restrict__ row_ptr,
                                int* __restrict__ nxt, int n, int E) {
    int i = blockIdx.x * 256 + threadIdx.x;
    if (i < n) {
        int v = incl[i] - cnt[i] + bsum[blockIdx.x];
        row_ptr[i] = v;
        nxt[i] = v;
    }
    if (i == 0) row_ptr[n] = E;
}

__global__ void fill_csr(const int* __restrict__ src, const int* __restrict__ dst,
                         int* __restrict__ nxt, int* __restrict__ csr_src, int E) {
    int i = blockIdx.x * blockDim.x + threadIdx.x;
    if (i < E) {
        int p = atomicAdd(&nxt[dst[i]], 1);
        csr_src[p] = src[i];
    }
}

// ---------------- dtype conversion helpers ----------------
__global__ void f32_to_f16_vec(const float* __restrict__ x, _Float16* __restrict__ y, int n4) {
    int i = blockIdx.x * 256 + threadIdx.x;
    if (i < n4) {
        float4 v = ((const float4*)x)[i];
        half4 h;
        h[0] = (_Float16)v.x; h[1] = (_Float16)v.y;
        h[2] = (_Float16)v.z; h[3] = (_Float16)v.w;
        ((half4*)y)[i] = h;
    }
}

// WT[m*K+k] = (fp16) W[k*M + m]   (W is [K,M] row-major fp32)
__global__ void transpose_w(const float* __restrict__ W, _Float16* __restrict__ WT,
                            int K, int M) {
    int i = blockIdx.x * 256 + threadIdx.x;
    if (i < K * M) {
        int m = i / K, k = i - m * K;
        WT[i] = (_Float16)W[k * M + m];
    }
}

// ---------------- fp16 MFMA GEMM: C[N,256] = A[N,K] @ B[K,256] -------------
// BT is B transposed: BT[m][k], fp16.  Output fp16.
#define GBM 128
#define GBK 32

__global__ __launch_bounds__(256)
void gemm_mfma(const _Float16* __restrict__ A, const _Float16* __restrict__ BT,
               _Float16* __restrict__ C, int N, int K) {
    __shared__ _Float16 As[GBM][GBK + 8];   // +8 halves pad: b128 2-way (free)
    __shared__ _Float16 Bs[GBM][GBK + 8];   // Bs[n][k]
    int tid  = threadIdx.x;
    int wave = tid >> 6, lane = tid & 63;
    int quad = lane >> 4, l16 = lane & 15;
    int row0 = blockIdx.y * GBM;
    int col0 = blockIdx.x * GBM;

    floatx4 acc[8][2];
    #pragma unroll
    for (int i = 0; i < 8; ++i)
        #pragma unroll
        for (int j = 0; j < 2; ++j)
            #pragma unroll
            for (int e = 0; e < 4; ++e) acc[i][j][e] = 0.f;

    for (int k0 = 0; k0 < K; k0 += GBK) {
        // stage A and BT tiles: 512 x 16B segments each; t -> 2 segs
        #pragma unroll
        for (int it = 0; it < 2; ++it) {
            int s = it * 256 + tid;
            int r = s >> 2, off = (s & 3) * 8;
            half8 v;
            #pragma unroll
            for (int q = 0; q < 8; ++q) v[q] = (_Float16)0.f;
            int gr = row0 + r;
            if (gr < N) v = *(const half8*)&A[(size_t)gr * K + k0 + off];
            *(half8*)&As[r][off] = v;
            half8 w = *(const half8*)&BT[(size_t)(col0 + r) * K + k0 + off];
            *(half8*)&Bs[r][off] = w;
        }
        __syncthreads();
        half8 bfrag[2];
        #pragma unroll
        for (int ct = 0; ct < 2; ++ct)
            bfrag[ct] = *(const half8*)&Bs[wave * 32 + ct * 16 + l16][quad * 8];
        #pragma unroll
        for (int rt = 0; rt < 8; ++rt) {
            half8 afrag = *(const half8*)&As[rt * 16 + l16][quad * 8];
            acc[rt][0] = __builtin_amdgcn_mfma_f32_16x16x32_f16(afrag, bfrag[0], acc[rt][0], 0, 0, 0);
            acc[rt][1] = __builtin_amdgcn_mfma_f32_16x16x32_f16(afrag, bfrag[1], acc[rt][1], 0, 0, 0);
        }
        __syncthreads();
    }
    // epilogue: C/D layout col=lane&15, row=quad*4+reg
    #pragma unroll
    for (int rt = 0; rt < 8; ++rt) {
        #pragma unroll
        for (int reg = 0; reg < 4; ++reg) {
            int gr = row0 + rt * 16 + quad * 4 + reg;
            if (gr < N) {
                #pragma unroll
                for (int ct = 0; ct < 2; ++ct) {
                    int gc = col0 + wave * 32 + ct * 16 + l16;
                    C[(size_t)gr * 256 + gc] = (_Float16)acc[rt][ct][reg];
                }
            }
        }
    }
}

// ---------------- attention coefficients el/er for H=4, D=64 ----------------
__global__ __launch_bounds__(256)
void attn_lr(const _Float16* __restrict__ h16, const float* __restrict__ al,
             const float* __restrict__ ar, float* __restrict__ el,
             float* __restrict__ er, int NH) {   // NH = N*4
    int gt = blockIdx.x * 256 + threadIdx.x;
    int w = gt >> 6;
    int lane = threadIdx.x & 63;
    if (w >= NH) return;
    int hd = w & 3;
    float v = (float)h16[(size_t)w * 64 + lane];
    float l = v * al[hd * 64 + lane];
    float r = v * ar[hd * 64 + lane];
    #pragma unroll
    for (int o = 32; o; o >>= 1) { l += __shfl_down(l, o); r += __shfl_down(r, o); }
    if (lane == 0) { el[w] = l; er[w] = r; }
}

// ---------------- softmax + aggregate + bias + ELU, H=4, D=64 --------------
// fp16 gather table, fp32 accumulate, fp16 output.
__global__ __launch_bounds__(256)
void gat_agg(const _Float16* __restrict__ h16, const float* __restrict__ el,
             const float* __restrict__ er, const int* __restrict__ row_ptr,
             const int* __restrict__ csr_src, const float* __restrict__ bias,
             _Float16* __restrict__ out, int N) {
    int n = blockIdx.x;
    int tid = threadIdx.x, wave = tid >> 6, lane = tid & 63;
    int beg = row_ptr[n], end = row_ptr[n + 1];
    __shared__ float er_n[4], m_sh[4], s_sh[4];
    __shared__ int   src_ch[64];
    __shared__ float a_ch[64][4];
    __shared__ float red[4][256];
    if (tid < 4) er_n[tid] = er[n * 4 + tid];
    __syncthreads();
    {   // softmax stats: wave w handles head w
        float ern = er_n[wave];
        float mx = -INFINITY;
        for (int j = beg + lane; j < end; j += 64) {
            int s = csr_src[j];
            float e = el[s * 4 + wave] + ern;
            e = e > 0.f ? e : 0.2f * e;
            mx = fmaxf(mx, e);
        }
        #pragma unroll
        for (int o = 1; o < 64; o <<= 1) mx = fmaxf(mx, __shfl_xor(mx, o));
        float sm = 0.f;
        for (int j = beg + lane; j < end; j += 64) {
            int s = csr_src[j];
            float e = el[s * 4 + wave] + ern;
            e = e > 0.f ? e : 0.2f * e;
            sm += __expf(e - mx);
        }
        #pragma unroll
        for (int o = 1; o < 64; o <<= 1) sm += __shfl_xor(sm, o);
        if (lane == 0) { m_sh[wave] = mx; s_sh[wave] = sm; }
    }
    __syncthreads();
    // gather: lane owns 4 contiguous cols (4*lane..4*lane+3); wave owns edge
    // stream e = wave, wave+4, ...; cross-wave reduce at the end.
    int hd = lane >> 4;
    floatx4 accv;
    accv[0] = accv[1] = accv[2] = accv[3] = 0.f;
    const _Float16* hb = h16 + 4 * lane;
    for (int j0 = beg; j0 < end; j0 += 64) {
        int cnt = min(64, end - j0);
        __syncthreads();
        if (tid < cnt) {
            int s = csr_src[j0 + tid];
            src_ch[tid] = s;
            #pragma unroll
            for (int q = 0; q < 4; ++q) {
                float e = el[s * 4 + q] + er_n[q];
                e = e > 0.f ? e : 0.2f * e;
                a_ch[tid][q] = __expf(e - m_sh[q]);
            }
        }
        __syncthreads();
        int e = wave;
        for (; e + 12 < cnt; e += 16) {
            int s0 = src_ch[e], s1 = src_ch[e + 4], s2 = src_ch[e + 8], s3 = src_ch[e + 12];
            float w0 = a_ch[e][hd], w1 = a_ch[e + 4][hd];
            float w2 = a_ch[e + 8][hd], w3 = a_ch[e + 12][hd];
            half4 v0 = *(const half4*)&hb[(size_t)s0 * 256];
            half4 v1 = *(const half4*)&hb[(size_t)s1 * 256];
            half4 v2 = *(const half4*)&hb[(size_t)s2 * 256];
            half4 v3 = *(const half4*)&hb[(size_t)s3 * 256];
            #pragma unroll
            for (int q = 0; q < 4; ++q)
                accv[q] += w0 * (float)v0[q] + w1 * (float)v1[q]
                         + w2 * (float)v2[q] + w3 * (float)v3[q];
        }
        for (; e < cnt; e += 4) {
            int s = src_ch[e];
            float wgt = a_ch[e][hd];
            half4 v = *(const half4*)&hb[(size_t)s * 256];
            #pragma unroll
            for (int q = 0; q < 4; ++q) accv[q] += wgt * (float)v[q];
        }
    }
    #pragma unroll
    for (int q = 0; q < 4; ++q) red[wave][lane * 4 + q] = accv[q];
    __syncthreads();
    int c = tid;
    float sv = s_sh[c >> 6];
    float inv_s = sv > 0.f ? 1.f / sv : 0.f;
    float v = (red[0][c] + red[1][c] + red[2][c] + red[3][c]) * inv_s + bias[c];
    v = v > 0.f ? v : (__expf(v) - 1.f);   // ELU
    out[(size_t)n * 256 + c] = (_Float16)v;
}

// ---------------- layer 3: GEMM [N,256]x[256,8] + attn coeffs --------------
__global__ __launch_bounds__(256)
void gemm3_attn(const _Float16* __restrict__ x, const float* __restrict__ W,
                const float* __restrict__ al, const float* __restrict__ ar,
                float* __restrict__ h3, float* __restrict__ el,
                float* __restrict__ er, int N) {
    __shared__ float Ws[256][9];
    int tid = threadIdx.x;
    #pragma unroll
    for (int d = 0; d < 8; ++d) Ws[tid][d] = W[tid * 8 + d];
    __syncthreads();
    int lane = tid & 63;
    int n = blockIdx.x * 4 + (tid >> 6);
    if (n >= N) return;
    float acc[8] = {};
    #pragma unroll
    for (int i = 0; i < 4; ++i) {
        int k = i * 64 + lane;
        float xv = (float)x[(size_t)n * 256 + k];
        #pragma unroll
        for (int d = 0; d < 8; ++d) acc[d] += xv * Ws[k][d];
    }
    #pragma unroll
    for (int d = 0; d < 8; ++d) {
        #pragma unroll
        for (int o = 32; o; o >>= 1) acc[d] += __shfl_down(acc[d], o);
    }
    if (lane == 0) {
        float l = 0.f, r = 0.f;
        #pragma unroll
        for (int d = 0; d < 8; ++d) {
            h3[n * 8 + d] = acc[d];
            l += acc[d] * al[d];
            r += acc[d] * ar[d];
        }
        el[n] = l;
        er[n] = r;
    }
}

// ---------------- layer 3 softmax + aggregate (H=1, D=8) -------------------
__global__ __launch_bounds__(256)
void gat_agg3(const float* __restrict__ h3, const float* __restrict__ el,
              const float* __restrict__ er, const int* __restrict__ row_ptr,
              const int* __restrict__ csr_src, const float* __restrict__ bias,
              float* __restrict__ out, int N) {
    int tid = threadIdx.x;
    int lane = tid & 63;
    int n = blockIdx.x * 4 + (tid >> 6);
    if (n >= N) return;
    int beg = row_ptr[n], end = row_ptr[n + 1];
    float er_n = er[n];
    float mx = -INFINITY;
    for (int j = beg + lane; j < end; j += 64) {
        float e = el[csr_src[j]] + er_n; e = e > 0.f ? e : 0.2f * e;
        mx = fmaxf(mx, e);
    }
    #pragma unroll
    for (int o = 1; o < 64; o <<= 1) mx = fmaxf(mx, __shfl_xor(mx, o));
    float sm = 0.f;
    for (int j = beg + lane; j < end; j += 64) {
        float e = el[csr_src[j]] + er_n; e = e > 0.f ? e : 0.2f * e;
        sm += __expf(e - mx);
    }
    #pragma unroll
    for (int o = 1; o < 64; o <<= 1) sm += __shfl_xor(sm, o);
    float inv = sm > 0.f ? 1.0f / sm : 0.0f;
    int g = lane >> 3, c = lane & 7;
    float acc = 0.f;
    for (int j = beg + g; j < end; j += 8) {
        int s = csr_src[j];
        float e = el[s] + er_n; e = e > 0.f ? e : 0.2f * e;
        float a = __expf(e - mx) * inv;
        acc += h3[s * 8 + c] * a;
    }
    acc += __shfl_xor(acc, 8);
    acc += __shfl_xor(acc, 16);
    acc += __shfl_xor(acc, 32);
    if (lane < 8) out[(size_t)n * 8 + lane] = acc + bias[lane];
}

// ---------------------------------------------------------------------------
static inline size_t align_up(size_t x, size_t a) { return (x + a - 1) & ~(a - 1); }

extern "C" void kernel_launch(void* const* d_in, const int* in_sizes, int n_in,
                              void* d_out, int out_size, void* d_ws, size_t ws_size,
                              hipStream_t stream) {
    const float* feat = (const float*)d_in[0];
    const int*   src  = (const int*)d_in[1];
    const int*   dst  = (const int*)d_in[2];
    const float* W1   = (const float*)d_in[3];
    const float* al1  = (const float*)d_in[4];
    const float* ar1  = (const float*)d_in[5];
    const float* b1   = (const float*)d_in[6];
    const float* W2   = (const float*)d_in[7];
    const float* al2  = (const float*)d_in[8];
    const float* ar2  = (const float*)d_in[9];
    const float* b2   = (const float*)d_in[10];
    const float* W3   = (const float*)d_in[11];
    const float* al3  = (const float*)d_in[12];
    const float* ar3  = (const float*)d_in[13];
    const float* b3   = (const float*)d_in[14];

    const int N = in_sizes[0] / 128;
    const int E = in_sizes[1];

    char* w = (char*)d_ws;
    _Float16* bufA16 = (_Float16*)w; w += align_up((size_t)N * 256 * 2, 256);
    _Float16* bufB16 = (_Float16*)w; w += align_up((size_t)N * 256 * 2, 256);
    _Float16* feat16 = (_Float16*)w; w += align_up((size_t)N * 128 * 2, 256);
    _Float16* W1T    = (_Float16*)w; w += align_up((size_t)256 * 128 * 2, 256);
    _Float16* W2T    = (_Float16*)w; w += align_up((size_t)256 * 256 * 2, 256);
    float* el      = (float*)w; w += align_up((size_t)N * 4 * 4, 256);
    float* er      = (float*)w; w += align_up((size_t)N * 4 * 4, 256);
    float* h3      = (float*)w; w += align_up((size_t)N * 8 * 4, 256);
    int*   cnt     = (int*)w;   w += align_up((size_t)N * 4, 256);
    int*   incl    = (int*)w;   w += align_up((size_t)N * 4, 256);
    int*   bsum    = (int*)w;   w += align_up(256 * 4, 256);
    int*   row_ptr = (int*)w;   w += align_up(((size_t)N + 1) * 4, 256);
    int*   nxt     = (int*)w;   w += align_up((size_t)N * 4, 256);
    int*   csr_src = (int*)w;   w += align_up((size_t)E * 4, 256);
    (void)ws_size; (void)n_in; (void)out_size;

    const int G1 = (N + 255) / 256;
    const int GE = (E + 255) / 256;

    // ---- CSR build (dst identical for all layers) ----
    hipMemsetAsync(cnt, 0, (size_t)N * 4, stream);
    count_edges<<<GE, 256, 0, stream>>>(dst, cnt, E);
    scan_block<<<G1, 256, 0, stream>>>(cnt, incl, bsum, N);
    scan_sums<<<1, 256, 0, stream>>>(bsum, G1);
    finalize_rowptr<<<G1, 256, 0, stream>>>(incl, cnt, bsum, row_ptr, nxt, N, E);
    fill_csr<<<GE, 256, 0, stream>>>(src, dst, nxt, csr_src, E);

    // ---- dtype prep ----
    f32_to_f16_vec<<<((N * 128 / 4) + 255) / 256, 256, 0, stream>>>(feat, feat16, N * 128 / 4);
    transpose_w<<<(128 * 256 + 255) / 256, 256, 0, stream>>>(W1, W1T, 128, 256);
    transpose_w<<<(256 * 256 + 255) / 256, 256, 0, stream>>>(W2, W2T, 256, 256);

    dim3 ggrid(2, (N + GBM - 1) / GBM);

    // ---- layer 1 ----
    gemm_mfma<<<ggrid, 256, 0, stream>>>(feat16, W1T, bufA16, N, 128);
    attn_lr<<<(N * 4 * 64 + 255) / 256, 256, 0, stream>>>(bufA16, al1, ar1, el, er, N * 4);
    gat_agg<<<N, 256, 0, stream>>>(bufA16, el, er, row_ptr, csr_src, b1, bufB16, N);

    // ---- layer 2 ----
    gemm_mfma<<<ggrid, 256, 0, stream>>>(bufB16, W2T, bufA16, N, 256);
    attn_lr<<<(N * 4 * 64 + 255) / 256, 256, 0, stream>>>(bufA16, al2, ar2, el, er, N * 4);
    gat_agg<<<N, 256, 0, stream>>>(bufA16, el, er, row_ptr, csr_src, b2, bufB16, N);

    // ---- layer 3 ----
    gemm3_attn<<<(N + 3) / 4, 256, 0, stream>>>(bufB16, W3, al3, ar3, h3, el, er, N);
    gat_agg3<<<(N + 3) / 4, 256, 0, stream>>>(h3, el, er, row_ptr, csr_src, b3,
                                              (float*)d_out, N);
}

// Round 3
// 475.444 us; speedup vs baseline: 1.5945x; 1.2469x over previous
//
#include <hip/hip_runtime.h>
#include <math.h>

// ---------------------------------------------------------------------------
// GAT 3-layer forward.  N=50000 nodes, E=800000 edges.
// Round 3: gat_agg redesigned as 32-lanes-per-node, no LDS, no barriers,
// 4-deep unrolled b128 gather. fp16 activations, fp32 accumulation.
// ---------------------------------------------------------------------------

typedef _Float16 half8 __attribute__((ext_vector_type(8)));
typedef _Float16 half4 __attribute__((ext_vector_type(4)));
typedef float    floatx4 __attribute__((ext_vector_type(4)));

__device__ __forceinline__ float leaky02(float x) { return x > 0.f ? x : 0.2f * x; }

// ---------------- CSR build ----------------
__global__ void count_edges(const int* __restrict__ dst, int* __restrict__ cnt, int E) {
    int i = blockIdx.x * blockDim.x + threadIdx.x;
    if (i < E) atomicAdd(&cnt[dst[i]], 1);
}

__global__ void scan_block(const int* __restrict__ cnt, int* __restrict__ incl,
                           int* __restrict__ bsum, int n) {
    __shared__ int sh[256];
    int tid = threadIdx.x;
    int i = blockIdx.x * 256 + tid;
    int v = (i < n) ? cnt[i] : 0;
    sh[tid] = v;
    __syncthreads();
    for (int o = 1; o < 256; o <<= 1) {
        int t = (tid >= o) ? sh[tid - o] : 0;
        __syncthreads();
        sh[tid] += t;
        __syncthreads();
    }
    if (i < n) incl[i] = sh[tid];
    if (tid == 255) bsum[blockIdx.x] = sh[255];
}

__global__ void scan_sums(int* __restrict__ bsum, int g) {
    __shared__ int sh[256];
    int tid = threadIdx.x;
    int v = (tid < g) ? bsum[tid] : 0;
    sh[tid] = v;
    __syncthreads();
    for (int o = 1; o < 256; o <<= 1) {
        int t = (tid >= o) ? sh[tid - o] : 0;
        __syncthreads();
        sh[tid] += t;
        __syncthreads();
    }
    if (tid < g) bsum[tid] = sh[tid] - v;   // exclusive
}

__global__ void finalize_rowptr(const int* __restrict__ incl, const int* __restrict__ cnt,
                                const int* __restrict__ bsum, int* __restrict__ row_ptr,
                                int* __restrict__ nxt, int n, int E) {
    int i = blockIdx.x * 256 + threadIdx.x;
    if (i < n) {
        int v = incl[i] - cnt[i] + bsum[blockIdx.x];
        row_ptr[i] = v;
        nxt[i] = v;
    }
    if (i == 0) row_ptr[n] = E;
}

__global__ void fill_csr(const int* __restrict__ src, const int* __restrict__ dst,
                         int* __restrict__ nxt, int* __restrict__ csr_src, int E) {
    int i = blockIdx.x * blockDim.x + threadIdx.x;
    if (i < E) {
        int p = atomicAdd(&nxt[dst[i]], 1);
        csr_src[p] = src[i];
    }
}

// ---------------- dtype conversion helpers ----------------
__global__ void f32_to_f16_vec(const float* __restrict__ x, _Float16* __restrict__ y, int n4) {
    int i = blockIdx.x * 256 + threadIdx.x;
    if (i < n4) {
        float4 v = ((const float4*)x)[i];
        half4 h;
        h[0] = (_Float16)v.x; h[1] = (_Float16)v.y;
        h[2] = (_Float16)v.z; h[3] = (_Float16)v.w;
        ((half4*)y)[i] = h;
    }
}

// WT[m*K+k] = (fp16) W[k*M + m]   (W is [K,M] row-major fp32)
__global__ void transpose_w(const float* __restrict__ W, _Float16* __restrict__ WT,
                            int K, int M) {
    int i = blockIdx.x * 256 + threadIdx.x;
    if (i < K * M) {
        int m = i / K, k = i - m * K;
        WT[i] = (_Float16)W[k * M + m];
    }
}

// ---------------- fp16 MFMA GEMM: C[N,256] = A[N,K] @ B[K,256] -------------
#define GBM 128
#define GBK 32

__global__ __launch_bounds__(256)
void gemm_mfma(const _Float16* __restrict__ A, const _Float16* __restrict__ BT,
               _Float16* __restrict__ C, int N, int K) {
    __shared__ _Float16 As[GBM][GBK + 8];
    __shared__ _Float16 Bs[GBM][GBK + 8];
    int tid  = threadIdx.x;
    int wave = tid >> 6, lane = tid & 63;
    int quad = lane >> 4, l16 = lane & 15;
    int row0 = blockIdx.y * GBM;
    int col0 = blockIdx.x * GBM;

    floatx4 acc[8][2];
    #pragma unroll
    for (int i = 0; i < 8; ++i)
        #pragma unroll
        for (int j = 0; j < 2; ++j)
            #pragma unroll
            for (int e = 0; e < 4; ++e) acc[i][j][e] = 0.f;

    for (int k0 = 0; k0 < K; k0 += GBK) {
        #pragma unroll
        for (int it = 0; it < 2; ++it) {
            int s = it * 256 + tid;
            int r = s >> 2, off = (s & 3) * 8;
            half8 v;
            #pragma unroll
            for (int q = 0; q < 8; ++q) v[q] = (_Float16)0.f;
            int gr = row0 + r;
            if (gr < N) v = *(const half8*)&A[(size_t)gr * K + k0 + off];
            *(half8*)&As[r][off] = v;
            half8 w = *(const half8*)&BT[(size_t)(col0 + r) * K + k0 + off];
            *(half8*)&Bs[r][off] = w;
        }
        __syncthreads();
        half8 bfrag[2];
        #pragma unroll
        for (int ct = 0; ct < 2; ++ct)
            bfrag[ct] = *(const half8*)&Bs[wave * 32 + ct * 16 + l16][quad * 8];
        #pragma unroll
        for (int rt = 0; rt < 8; ++rt) {
            half8 afrag = *(const half8*)&As[rt * 16 + l16][quad * 8];
            acc[rt][0] = __builtin_amdgcn_mfma_f32_16x16x32_f16(afrag, bfrag[0], acc[rt][0], 0, 0, 0);
            acc[rt][1] = __builtin_amdgcn_mfma_f32_16x16x32_f16(afrag, bfrag[1], acc[rt][1], 0, 0, 0);
        }
        __syncthreads();
    }
    #pragma unroll
    for (int rt = 0; rt < 8; ++rt) {
        #pragma unroll
        for (int reg = 0; reg < 4; ++reg) {
            int gr = row0 + rt * 16 + quad * 4 + reg;
            if (gr < N) {
                #pragma unroll
                for (int ct = 0; ct < 2; ++ct) {
                    int gc = col0 + wave * 32 + ct * 16 + l16;
                    C[(size_t)gr * 256 + gc] = (_Float16)acc[rt][ct][reg];
                }
            }
        }
    }
}

// ---------------- attention coefficients el/er for H=4, D=64 ----------------
__global__ __launch_bounds__(256)
void attn_lr(const _Float16* __restrict__ h16, const float* __restrict__ al,
             const float* __restrict__ ar, float* __restrict__ el,
             float* __restrict__ er, int NH) {   // NH = N*4
    int gt = blockIdx.x * 256 + threadIdx.x;
    int w = gt >> 6;
    int lane = threadIdx.x & 63;
    if (w >= NH) return;
    int hd = w & 3;
    float v = (float)h16[(size_t)w * 64 + lane];
    float l = v * al[hd * 64 + lane];
    float r = v * ar[hd * 64 + lane];
    #pragma unroll
    for (int o = 32; o; o >>= 1) { l += __shfl_down(l, o); r += __shfl_down(r, o); }
    if (lane == 0) { el[w] = l; er[w] = r; }
}

// ---------------- softmax + aggregate + bias + ELU, H=4, D=64 --------------
// 32 lanes per node (8 nodes / block). No LDS, no barriers.
// Lane owns 8 contiguous cols (b128 per edge); head = l32>>3.
__global__ __launch_bounds__(256)
void gat_agg(const _Float16* __restrict__ h16, const float* __restrict__ el,
             const float* __restrict__ er, const int* __restrict__ row_ptr,
             const int* __restrict__ csr_src, const float* __restrict__ bias,
             _Float16* __restrict__ out, int N) {
    int tid = threadIdx.x;
    int l32 = tid & 31;
    int node = blockIdx.x * 8 + (tid >> 5);
    if (node >= N) return;
    int beg = row_ptr[node], end = row_ptr[node + 1];
    int deg = end - beg;
    int hd = l32 >> 3;

    float er0 = er[node * 4 + 0], er1 = er[node * 4 + 1];
    float er2 = er[node * 4 + 2], er3 = er[node * 4 + 3];

    float m0, m1, m2, m3, s0, s1, s2, s3;
    if (deg <= 32) {
        // fast path: lane j holds edge j's logits in registers, one pass
        float e0 = -INFINITY, e1 = -INFINITY, e2 = -INFINITY, e3 = -INFINITY;
        bool act = l32 < deg;
        if (act) {
            int sv = csr_src[beg + l32];
            e0 = leaky02(el[sv * 4 + 0] + er0);
            e1 = leaky02(el[sv * 4 + 1] + er1);
            e2 = leaky02(el[sv * 4 + 2] + er2);
            e3 = leaky02(el[sv * 4 + 3] + er3);
        }
        m0 = e0; m1 = e1; m2 = e2; m3 = e3;
        #pragma unroll
        for (int msk = 1; msk < 32; msk <<= 1) {
            m0 = fmaxf(m0, __shfl_xor(m0, msk));
            m1 = fmaxf(m1, __shfl_xor(m1, msk));
            m2 = fmaxf(m2, __shfl_xor(m2, msk));
            m3 = fmaxf(m3, __shfl_xor(m3, msk));
        }
        s0 = act ? __expf(e0 - m0) : 0.f;
        s1 = act ? __expf(e1 - m1) : 0.f;
        s2 = act ? __expf(e2 - m2) : 0.f;
        s3 = act ? __expf(e3 - m3) : 0.f;
        #pragma unroll
        for (int msk = 1; msk < 32; msk <<= 1) {
            s0 += __shfl_xor(s0, msk);
            s1 += __shfl_xor(s1, msk);
            s2 += __shfl_xor(s2, msk);
            s3 += __shfl_xor(s3, msk);
        }
    } else {
        m0 = m1 = m2 = m3 = -INFINITY;
        for (int j = beg + l32; j < end; j += 32) {
            int sv = csr_src[j];
            m0 = fmaxf(m0, leaky02(el[sv * 4 + 0] + er0));
            m1 = fmaxf(m1, leaky02(el[sv * 4 + 1] + er1));
            m2 = fmaxf(m2, leaky02(el[sv * 4 + 2] + er2));
            m3 = fmaxf(m3, leaky02(el[sv * 4 + 3] + er3));
        }
        #pragma unroll
        for (int msk = 1; msk < 32; msk <<= 1) {
            m0 = fmaxf(m0, __shfl_xor(m0, msk));
            m1 = fmaxf(m1, __shfl_xor(m1, msk));
            m2 = fmaxf(m2, __shfl_xor(m2, msk));
            m3 = fmaxf(m3, __shfl_xor(m3, msk));
        }
        s0 = s1 = s2 = s3 = 0.f;
        for (int j = beg + l32; j < end; j += 32) {
            int sv = csr_src[j];
            s0 += __expf(leaky02(el[sv * 4 + 0] + er0) - m0);
            s1 += __expf(leaky02(el[sv * 4 + 1] + er1) - m1);
            s2 += __expf(leaky02(el[sv * 4 + 2] + er2) - m2);
            s3 += __expf(leaky02(el[sv * 4 + 3] + er3) - m3);
        }
        #pragma unroll
        for (int msk = 1; msk < 32; msk <<= 1) {
            s0 += __shfl_xor(s0, msk);
            s1 += __shfl_xor(s1, msk);
            s2 += __shfl_xor(s2, msk);
            s3 += __shfl_xor(s3, msk);
        }
    }
    // my head's constants
    float mh  = (hd & 2) ? ((hd & 1) ? m3 : m2) : ((hd & 1) ? m1 : m0);
    float sh_ = (hd & 2) ? ((hd & 1) ? s3 : s2) : ((hd & 1) ? s1 : s0);
    float erh = (hd & 2) ? ((hd & 1) ? er3 : er2) : ((hd & 1) ? er1 : er0);
    float ih  = sh_ > 0.f ? 1.f / sh_ : 0.f;

    const _Float16* hb = h16 + l32 * 8;
    float acc[8] = {};
    int j = beg;
    for (; j + 4 <= end; j += 4) {
        int sa = csr_src[j], sb = csr_src[j + 1], sc = csr_src[j + 2], sd = csr_src[j + 3];
        float wa = __expf(leaky02(el[sa * 4 + hd] + erh) - mh) * ih;
        float wb = __expf(leaky02(el[sb * 4 + hd] + erh) - mh) * ih;
        float wc = __expf(leaky02(el[sc * 4 + hd] + erh) - mh) * ih;
        float wd = __expf(leaky02(el[sd * 4 + hd] + erh) - mh) * ih;
        half8 va = *(const half8*)&hb[(size_t)sa * 256];
        half8 vb = *(const half8*)&hb[(size_t)sb * 256];
        half8 vc = *(const half8*)&hb[(size_t)sc * 256];
        half8 vd = *(const half8*)&hb[(size_t)sd * 256];
        #pragma unroll
        for (int q = 0; q < 8; ++q)
            acc[q] += wa * (float)va[q] + wb * (float)vb[q]
                    + wc * (float)vc[q] + wd * (float)vd[q];
    }
    for (; j < end; ++j) {
        int sv = csr_src[j];
        float w = __expf(leaky02(el[sv * 4 + hd] + erh) - mh) * ih;
        half8 v = *(const half8*)&hb[(size_t)sv * 256];
        #pragma unroll
        for (int q = 0; q < 8; ++q) acc[q] += w * (float)v[q];
    }
    half8 o;
    #pragma unroll
    for (int q = 0; q < 8; ++q) {
        float v = acc[q] + bias[l32 * 8 + q];
        v = v > 0.f ? v : (__expf(v) - 1.f);   // ELU
        o[q] = (_Float16)v;
    }
    *(half8*)&out[(size_t)node * 256 + l32 * 8] = o;
}

// ---------------- layer 3: GEMM [N,256]x[256,8] + attn coeffs --------------
__global__ __launch_bounds__(256)
void gemm3_attn(const _Float16* __restrict__ x, const float* __restrict__ W,
                const float* __restrict__ al, const float* __restrict__ ar,
                float* __restrict__ h3, float* __restrict__ el,
                float* __restrict__ er, int N) {
    __shared__ float Ws[256][9];
    int tid = threadIdx.x;
    #pragma unroll
    for (int d = 0; d < 8; ++d) Ws[tid][d] = W[tid * 8 + d];
    __syncthreads();
    int lane = tid & 63;
    int n = blockIdx.x * 4 + (tid >> 6);
    if (n >= N) return;
    float acc[8] = {};
    #pragma unroll
    for (int i = 0; i < 4; ++i) {
        int k = i * 64 + lane;
        float xv = (float)x[(size_t)n * 256 + k];
        #pragma unroll
        for (int d = 0; d < 8; ++d) acc[d] += xv * Ws[k][d];
    }
    #pragma unroll
    for (int d = 0; d < 8; ++d) {
        #pragma unroll
        for (int o = 32; o; o >>= 1) acc[d] += __shfl_down(acc[d], o);
    }
    if (lane == 0) {
        float l = 0.f, r = 0.f;
        #pragma unroll
        for (int d = 0; d < 8; ++d) {
            h3[n * 8 + d] = acc[d];
            l += acc[d] * al[d];
            r += acc[d] * ar[d];
        }
        el[n] = l;
        er[n] = r;
    }
}

// ---------------- layer 3 softmax + aggregate (H=1, D=8) -------------------
__global__ __launch_bounds__(256)
void gat_agg3(const float* __restrict__ h3, const float* __restrict__ el,
              const float* __restrict__ er, const int* __restrict__ row_ptr,
              const int* __restrict__ csr_src, const float* __restrict__ bias,
              float* __restrict__ out, int N) {
    int tid = threadIdx.x;
    int lane = tid & 63;
    int n = blockIdx.x * 4 + (tid >> 6);
    if (n >= N) return;
    int beg = row_ptr[n], end = row_ptr[n + 1];
    float er_n = er[n];
    float mx = -INFINITY;
    for (int j = beg + lane; j < end; j += 64) {
        float e = el[csr_src[j]] + er_n; e = e > 0.f ? e : 0.2f * e;
        mx = fmaxf(mx, e);
    }
    #pragma unroll
    for (int o = 1; o < 64; o <<= 1) mx = fmaxf(mx, __shfl_xor(mx, o));
    float sm = 0.f;
    for (int j = beg + lane; j < end; j += 64) {
        float e = el[csr_src[j]] + er_n; e = e > 0.f ? e : 0.2f * e;
        sm += __expf(e - mx);
    }
    #pragma unroll
    for (int o = 1; o < 64; o <<= 1) sm += __shfl_xor(sm, o);
    float inv = sm > 0.f ? 1.0f / sm : 0.0f;
    int g = lane >> 3, c = lane & 7;
    float acc = 0.f;
    for (int j = beg + g; j < end; j += 8) {
        int s = csr_src[j];
        float e = el[s] + er_n; e = e > 0.f ? e : 0.2f * e;
        float a = __expf(e - mx) * inv;
        acc += h3[s * 8 + c] * a;
    }
    acc += __shfl_xor(acc, 8);
    acc += __shfl_xor(acc, 16);
    acc += __shfl_xor(acc, 32);
    if (lane < 8) out[(size_t)n * 8 + lane] = acc + bias[lane];
}

// ---------------------------------------------------------------------------
static inline size_t align_up(size_t x, size_t a) { return (x + a - 1) & ~(a - 1); }

extern "C" void kernel_launch(void* const* d_in, const int* in_sizes, int n_in,
                              void* d_out, int out_size, void* d_ws, size_t ws_size,
                              hipStream_t stream) {
    const float* feat = (const float*)d_in[0];
    const int*   src  = (const int*)d_in[1];
    const int*   dst  = (const int*)d_in[2];
    const float* W1   = (const float*)d_in[3];
    const float* al1  = (const float*)d_in[4];
    const float* ar1  = (const float*)d_in[5];
    const float* b1   = (const float*)d_in[6];
    const float* W2   = (const float*)d_in[7];
    const float* al2  = (const float*)d_in[8];
    const float* ar2  = (const float*)d_in[9];
    const float* b2   = (const float*)d_in[10];
    const float* W3   = (const float*)d_in[11];
    const float* al3  = (const float*)d_in[12];
    const float* ar3  = (const float*)d_in[13];
    const float* b3   = (const float*)d_in[14];

    const int N = in_sizes[0] / 128;
    const int E = in_sizes[1];

    char* w = (char*)d_ws;
    _Float16* bufA16 = (_Float16*)w; w += align_up((size_t)N * 256 * 2, 256);
    _Float16* bufB16 = (_Float16*)w; w += align_up((size_t)N * 256 * 2, 256);
    _Float16* feat16 = (_Float16*)w; w += align_up((size_t)N * 128 * 2, 256);
    _Float16* W1T    = (_Float16*)w; w += align_up((size_t)256 * 128 * 2, 256);
    _Float16* W2T    = (_Float16*)w; w += align_up((size_t)256 * 256 * 2, 256);
    float* el      = (float*)w; w += align_up((size_t)N * 4 * 4, 256);
    float* er      = (float*)w; w += align_up((size_t)N * 4 * 4, 256);
    float* h3      = (float*)w; w += align_up((size_t)N * 8 * 4, 256);
    int*   cnt     = (int*)w;   w += align_up((size_t)N * 4, 256);
    int*   incl    = (int*)w;   w += align_up((size_t)N * 4, 256);
    int*   bsum    = (int*)w;   w += align_up(256 * 4, 256);
    int*   row_ptr = (int*)w;   w += align_up(((size_t)N + 1) * 4, 256);
    int*   nxt     = (int*)w;   w += align_up((size_t)N * 4, 256);
    int*   csr_src = (int*)w;   w += align_up((size_t)E * 4, 256);
    (void)ws_size; (void)n_in; (void)out_size;

    const int G1 = (N + 255) / 256;
    const int GE = (E + 255) / 256;

    // ---- CSR build (dst identical for all layers) ----
    hipMemsetAsync(cnt, 0, (size_t)N * 4, stream);
    count_edges<<<GE, 256, 0, stream>>>(dst, cnt, E);
    scan_block<<<G1, 256, 0, stream>>>(cnt, incl, bsum, N);
    scan_sums<<<1, 256, 0, stream>>>(bsum, G1);
    finalize_rowptr<<<G1, 256, 0, stream>>>(incl, cnt, bsum, row_ptr, nxt, N, E);
    fill_csr<<<GE, 256, 0, stream>>>(src, dst, nxt, csr_src, E);

    // ---- dtype prep ----
    f32_to_f16_vec<<<((N * 128 / 4) + 255) / 256, 256, 0, stream>>>(feat, feat16, N * 128 / 4);
    transpose_w<<<(128 * 256 + 255) / 256, 256, 0, stream>>>(W1, W1T, 128, 256);
    transpose_w<<<(256 * 256 + 255) / 256, 256, 0, stream>>>(W2, W2T, 256, 256);

    dim3 ggrid(2, (N + GBM - 1) / GBM);
    const int GA = (N + 7) / 8;

    // ---- layer 1 ----
    gemm_mfma<<<ggrid, 256, 0, stream>>>(feat16, W1T, bufA16, N, 128);
    attn_lr<<<(N * 4 * 64 + 255) / 256, 256, 0, stream>>>(bufA16, al1, ar1, el, er, N * 4);
    gat_agg<<<GA, 256, 0, stream>>>(bufA16, el, er, row_ptr, csr_src, b1, bufB16, N);

    // ---- layer 2 ----
    gemm_mfma<<<ggrid, 256, 0, stream>>>(bufB16, W2T, bufA16, N, 256);
    attn_lr<<<(N * 4 * 64 + 255) / 256, 256, 0, stream>>>(bufA16, al2, ar2, el, er, N * 4);
    gat_agg<<<GA, 256, 0, stream>>>(bufA16, el, er, row_ptr, csr_src, b2, bufB16, N);

    // ---- layer 3 ----
    gemm3_attn<<<(N + 3) / 4, 256, 0, stream>>>(bufB16, W3, al3, ar3, h3, el, er, N);
    gat_agg3<<<(N + 3) / 4, 256, 0, stream>>>(h3, el, er, row_ptr, csr_src, b3,
                                              (float*)d_out, N);
}

// Round 5
// 433.253 us; speedup vs baseline: 1.7498x; 1.0974x over previous
//
#include <hip/hip_runtime.h>
#include <math.h>

// ---------------------------------------------------------------------------
// GAT 3-layer forward.  N=50000 nodes, E=800000 edges.
// Round 5: round-3 proven gat_agg/gat_agg3 + merged transpose + fp32-A
// staging GEMM (drops convert pass) + attn_lr with xor-based 8-lane reduce.
// ---------------------------------------------------------------------------

typedef _Float16 half8 __attribute__((ext_vector_type(8)));
typedef _Float16 half4 __attribute__((ext_vector_type(4)));
typedef float    floatx4 __attribute__((ext_vector_type(4)));

__device__ __forceinline__ float leaky02(float x) { return x > 0.f ? x : 0.2f * x; }

// ---------------- CSR build ----------------
__global__ void count_edges(const int* __restrict__ dst, int* __restrict__ cnt, int E) {
    int i = blockIdx.x * blockDim.x + threadIdx.x;
    if (i < E) atomicAdd(&cnt[dst[i]], 1);
}

__global__ void scan_block(const int* __restrict__ cnt, int* __restrict__ incl,
                           int* __restrict__ bsum, int n) {
    __shared__ int sh[256];
    int tid = threadIdx.x;
    int i = blockIdx.x * 256 + tid;
    int v = (i < n) ? cnt[i] : 0;
    sh[tid] = v;
    __syncthreads();
    for (int o = 1; o < 256; o <<= 1) {
        int t = (tid >= o) ? sh[tid - o] : 0;
        __syncthreads();
        sh[tid] += t;
        __syncthreads();
    }
    if (i < n) incl[i] = sh[tid];
    if (tid == 255) bsum[blockIdx.x] = sh[255];
}

__global__ void scan_sums(int* __restrict__ bsum, int g) {
    __shared__ int sh[256];
    int tid = threadIdx.x;
    int v = (tid < g) ? bsum[tid] : 0;
    sh[tid] = v;
    __syncthreads();
    for (int o = 1; o < 256; o <<= 1) {
        int t = (tid >= o) ? sh[tid - o] : 0;
        __syncthreads();
        sh[tid] += t;
        __syncthreads();
    }
    if (tid < g) bsum[tid] = sh[tid] - v;   // exclusive
}

__global__ void finalize_rowptr(const int* __restrict__ incl, const int* __restrict__ cnt,
                                const int* __restrict__ bsum, int* __restrict__ row_ptr,
                                int* __restrict__ nxt, int n, int E) {
    int i = blockIdx.x * 256 + threadIdx.x;
    if (i < n) {
        int v = incl[i] - cnt[i] + bsum[blockIdx.x];
        row_ptr[i] = v;
        nxt[i] = v;
    }
    if (i == 0) row_ptr[n] = E;
}

__global__ void fill_csr(const int* __restrict__ src, const int* __restrict__ dst,
                         int* __restrict__ nxt, int* __restrict__ csr_src, int E) {
    int i = blockIdx.x * blockDim.x + threadIdx.x;
    if (i < E) {
        int p = atomicAdd(&nxt[dst[i]], 1);
        csr_src[p] = src[i];
    }
}

// ---------------- W1+W2 transpose (one dispatch) ----------------
__global__ void transpose_w2(const float* __restrict__ W1, _Float16* __restrict__ W1T,
                             const float* __restrict__ W2, _Float16* __restrict__ W2T) {
    int i = blockIdx.x * 256 + threadIdx.x;
    if (i < 128 * 256) {
        int m = i >> 7, k = i & 127;
        W1T[i] = (_Float16)W1[k * 256 + m];
    } else {
        int j = i - 128 * 256;
        if (j < 256 * 256) {
            int m = j >> 8, k = j & 255;
            W2T[j] = (_Float16)W2[k * 256 + m];
        }
    }
}

// ---------------- MFMA GEMM: C[N,256] = A[N,K] @ B[K,256], fp16 out -------
#define GBM 128
#define GBK 32

template <bool AF32>
__global__ __launch_bounds__(256)
void gemm_mfma(const void* __restrict__ Ap, const _Float16* __restrict__ BT,
               _Float16* __restrict__ C, int N, int K) {
    __shared__ _Float16 As[GBM][GBK + 8];
    __shared__ _Float16 Bs[GBM][GBK + 8];
    int tid  = threadIdx.x;
    int wave = tid >> 6, lane = tid & 63;
    int quad = lane >> 4, l16 = lane & 15;
    int row0 = blockIdx.y * GBM;
    int col0 = blockIdx.x * GBM;

    floatx4 acc[8][2];
    #pragma unroll
    for (int i = 0; i < 8; ++i)
        #pragma unroll
        for (int j = 0; j < 2; ++j)
            #pragma unroll
            for (int e = 0; e < 4; ++e) acc[i][j][e] = 0.f;

    for (int k0 = 0; k0 < K; k0 += GBK) {
        if (AF32) {
            const float* Af = (const float*)Ap;
            #pragma unroll
            for (int it = 0; it < 4; ++it) {
                int s = it * 256 + tid;
                int r = s >> 3, off = (s & 7) * 4;
                float4 v = make_float4(0.f, 0.f, 0.f, 0.f);
                int gr = row0 + r;
                if (gr < N) v = *(const float4*)&Af[(size_t)gr * K + k0 + off];
                half4 hv;
                hv[0] = (_Float16)v.x; hv[1] = (_Float16)v.y;
                hv[2] = (_Float16)v.z; hv[3] = (_Float16)v.w;
                *(half4*)&As[r][off] = hv;
            }
        } else {
            const _Float16* Ah = (const _Float16*)Ap;
            #pragma unroll
            for (int it = 0; it < 2; ++it) {
                int s = it * 256 + tid;
                int r = s >> 2, off = (s & 3) * 8;
                half8 v;
                #pragma unroll
                for (int q = 0; q < 8; ++q) v[q] = (_Float16)0.f;
                int gr = row0 + r;
                if (gr < N) v = *(const half8*)&Ah[(size_t)gr * K + k0 + off];
                *(half8*)&As[r][off] = v;
            }
        }
        #pragma unroll
        for (int it = 0; it < 2; ++it) {
            int s = it * 256 + tid;
            int r = s >> 2, off = (s & 3) * 8;
            half8 w = *(const half8*)&BT[(size_t)(col0 + r) * K + k0 + off];
            *(half8*)&Bs[r][off] = w;
        }
        __syncthreads();
        half8 bfrag[2];
        #pragma unroll
        for (int ct = 0; ct < 2; ++ct)
            bfrag[ct] = *(const half8*)&Bs[wave * 32 + ct * 16 + l16][quad * 8];
        #pragma unroll
        for (int rt = 0; rt < 8; ++rt) {
            half8 afrag = *(const half8*)&As[rt * 16 + l16][quad * 8];
            acc[rt][0] = __builtin_amdgcn_mfma_f32_16x16x32_f16(afrag, bfrag[0], acc[rt][0], 0, 0, 0);
            acc[rt][1] = __builtin_amdgcn_mfma_f32_16x16x32_f16(afrag, bfrag[1], acc[rt][1], 0, 0, 0);
        }
        __syncthreads();
    }
    #pragma unroll
    for (int rt = 0; rt < 8; ++rt) {
        #pragma unroll
        for (int reg = 0; reg < 4; ++reg) {
            int gr = row0 + rt * 16 + quad * 4 + reg;
            if (gr < N) {
                #pragma unroll
                for (int ct = 0; ct < 2; ++ct) {
                    int gc = col0 + wave * 32 + ct * 16 + l16;
                    C[(size_t)gr * 256 + gc] = (_Float16)acc[rt][ct][reg];
                }
            }
        }
    }
}

// ---------------- attention coefficients el/er, H=4, D=64 ------------------
// 8 rows per wave, half8 load per lane; xor-reduce within each 8-lane group
// (masks 1,2,4 provably stay inside the group — no width-arg semantics).
__global__ __launch_bounds__(256)
void attn_lr(const _Float16* __restrict__ h16, const float* __restrict__ al,
             const float* __restrict__ ar, float* __restrict__ el,
             float* __restrict__ er, int NH) {   // NH = N*4 rows of 64
    int wid = (blockIdx.x * 256 + threadIdx.x) >> 6;
    int lane = threadIdx.x & 63;
    int r = lane >> 3, c = lane & 7;
    int row = wid * 8 + r;
    if (row >= NH) return;
    int hd = row & 3;
    half8 hv = *(const half8*)&h16[(size_t)row * 64 + c * 8];
    const float* alp = &al[hd * 64 + c * 8];
    const float* arp = &ar[hd * 64 + c * 8];
    float l = 0.f, rr = 0.f;
    #pragma unroll
    for (int q = 0; q < 8; ++q) {
        float v = (float)hv[q];
        l  += v * alp[q];
        rr += v * arp[q];
    }
    l  += __shfl_xor(l, 1);  l  += __shfl_xor(l, 2);  l  += __shfl_xor(l, 4);
    rr += __shfl_xor(rr, 1); rr += __shfl_xor(rr, 2); rr += __shfl_xor(rr, 4);
    if (c == 0) { el[row] = l; er[row] = rr; }
}

// ---------------- softmax + aggregate + bias + ELU, H=4, D=64 --------------
// Round-3 proven version: 32 lanes/node, unroll-4 b128 gather.
__global__ __launch_bounds__(256)
void gat_agg(const _Float16* __restrict__ h16, const float* __restrict__ el,
             const float* __restrict__ er, const int* __restrict__ row_ptr,
             const int* __restrict__ csr_src, const float* __restrict__ bias,
             _Float16* __restrict__ out, int N) {
    int tid = threadIdx.x;
    int l32 = tid & 31;
    int node = blockIdx.x * 8 + (tid >> 5);
    if (node >= N) return;
    int beg = row_ptr[node], end = row_ptr[node + 1];
    int deg = end - beg;
    int hd = l32 >> 3;

    float er0 = er[node * 4 + 0], er1 = er[node * 4 + 1];
    float er2 = er[node * 4 + 2], er3 = er[node * 4 + 3];

    float m0, m1, m2, m3, s0, s1, s2, s3;
    if (deg <= 32) {
        float e0 = -INFINITY, e1 = -INFINITY, e2 = -INFINITY, e3 = -INFINITY;
        bool act = l32 < deg;
        if (act) {
            int sv = csr_src[beg + l32];
            e0 = leaky02(el[sv * 4 + 0] + er0);
            e1 = leaky02(el[sv * 4 + 1] + er1);
            e2 = leaky02(el[sv * 4 + 2] + er2);
            e3 = leaky02(el[sv * 4 + 3] + er3);
        }
        m0 = e0; m1 = e1; m2 = e2; m3 = e3;
        #pragma unroll
        for (int msk = 1; msk < 32; msk <<= 1) {
            m0 = fmaxf(m0, __shfl_xor(m0, msk));
            m1 = fmaxf(m1, __shfl_xor(m1, msk));
            m2 = fmaxf(m2, __shfl_xor(m2, msk));
            m3 = fmaxf(m3, __shfl_xor(m3, msk));
        }
        s0 = act ? __expf(e0 - m0) : 0.f;
        s1 = act ? __expf(e1 - m1) : 0.f;
        s2 = act ? __expf(e2 - m2) : 0.f;
        s3 = act ? __expf(e3 - m3) : 0.f;
        #pragma unroll
        for (int msk = 1; msk < 32; msk <<= 1) {
            s0 += __shfl_xor(s0, msk);
            s1 += __shfl_xor(s1, msk);
            s2 += __shfl_xor(s2, msk);
            s3 += __shfl_xor(s3, msk);
        }
    } else {
        m0 = m1 = m2 = m3 = -INFINITY;
        for (int j = beg + l32; j < end; j += 32) {
            int sv = csr_src[j];
            m0 = fmaxf(m0, leaky02(el[sv * 4 + 0] + er0));
            m1 = fmaxf(m1, leaky02(el[sv * 4 + 1] + er1));
            m2 = fmaxf(m2, leaky02(el[sv * 4 + 2] + er2));
            m3 = fmaxf(m3, leaky02(el[sv * 4 + 3] + er3));
        }
        #pragma unroll
        for (int msk = 1; msk < 32; msk <<= 1) {
            m0 = fmaxf(m0, __shfl_xor(m0, msk));
            m1 = fmaxf(m1, __shfl_xor(m1, msk));
            m2 = fmaxf(m2, __shfl_xor(m2, msk));
            m3 = fmaxf(m3, __shfl_xor(m3, msk));
        }
        s0 = s1 = s2 = s3 = 0.f;
        for (int j = beg + l32; j < end; j += 32) {
            int sv = csr_src[j];
            s0 += __expf(leaky02(el[sv * 4 + 0] + er0) - m0);
            s1 += __expf(leaky02(el[sv * 4 + 1] + er1) - m1);
            s2 += __expf(leaky02(el[sv * 4 + 2] + er2) - m2);
            s3 += __expf(leaky02(el[sv * 4 + 3] + er3) - m3);
        }
        #pragma unroll
        for (int msk = 1; msk < 32; msk <<= 1) {
            s0 += __shfl_xor(s0, msk);
            s1 += __shfl_xor(s1, msk);
            s2 += __shfl_xor(s2, msk);
            s3 += __shfl_xor(s3, msk);
        }
    }
    float mh  = (hd & 2) ? ((hd & 1) ? m3 : m2) : ((hd & 1) ? m1 : m0);
    float sh_ = (hd & 2) ? ((hd & 1) ? s3 : s2) : ((hd & 1) ? s1 : s0);
    float erh = (hd & 2) ? ((hd & 1) ? er3 : er2) : ((hd & 1) ? er1 : er0);
    float ih  = sh_ > 0.f ? 1.f / sh_ : 0.f;

    const _Float16* hb = h16 + l32 * 8;
    float acc[8] = {};
    int j = beg;
    for (; j + 4 <= end; j += 4) {
        int sa = csr_src[j], sb = csr_src[j + 1], sc = csr_src[j + 2], sd = csr_src[j + 3];
        float wa = __expf(leaky02(el[sa * 4 + hd] + erh) - mh) * ih;
        float wb = __expf(leaky02(el[sb * 4 + hd] + erh) - mh) * ih;
        float wc = __expf(leaky02(el[sc * 4 + hd] + erh) - mh) * ih;
        float wd = __expf(leaky02(el[sd * 4 + hd] + erh) - mh) * ih;
        half8 va = *(const half8*)&hb[(size_t)sa * 256];
        half8 vb = *(const half8*)&hb[(size_t)sb * 256];
        half8 vc = *(const half8*)&hb[(size_t)sc * 256];
        half8 vd = *(const half8*)&hb[(size_t)sd * 256];
        #pragma unroll
        for (int q = 0; q < 8; ++q)
            acc[q] += wa * (float)va[q] + wb * (float)vb[q]
                    + wc * (float)vc[q] + wd * (float)vd[q];
    }
    for (; j < end; ++j) {
        int sv = csr_src[j];
        float w = __expf(leaky02(el[sv * 4 + hd] + erh) - mh) * ih;
        half8 v = *(const half8*)&hb[(size_t)sv * 256];
        #pragma unroll
        for (int q = 0; q < 8; ++q) acc[q] += w * (float)v[q];
    }
    half8 o;
    #pragma unroll
    for (int q = 0; q < 8; ++q) {
        float v = acc[q] + bias[l32 * 8 + q];
        v = v > 0.f ? v : (__expf(v) - 1.f);   // ELU
        o[q] = (_Float16)v;
    }
    *(half8*)&out[(size_t)node * 256 + l32 * 8] = o;
}

// ---------------- layer 3: GEMM [N,256]x[256,8] + attn coeffs --------------
__global__ __launch_bounds__(256)
void gemm3_attn(const _Float16* __restrict__ x, const float* __restrict__ W,
                const float* __restrict__ al, const float* __restrict__ ar,
                float* __restrict__ h3, float* __restrict__ el,
                float* __restrict__ er, int N) {
    __shared__ float Ws[256][9];
    int tid = threadIdx.x;
    #pragma unroll
    for (int d = 0; d < 8; ++d) Ws[tid][d] = W[tid * 8 + d];
    __syncthreads();
    int lane = tid & 63;
    int n = blockIdx.x * 4 + (tid >> 6);
    if (n >= N) return;
    float acc[8] = {};
    #pragma unroll
    for (int i = 0; i < 4; ++i) {
        int k = i * 64 + lane;
        float xv = (float)x[(size_t)n * 256 + k];
        #pragma unroll
        for (int d = 0; d < 8; ++d) acc[d] += xv * Ws[k][d];
    }
    #pragma unroll
    for (int d = 0; d < 8; ++d) {
        #pragma unroll
        for (int o = 32; o; o >>= 1) acc[d] += __shfl_down(acc[d], o);
    }
    if (lane == 0) {
        float l = 0.f, r = 0.f;
        #pragma unroll
        for (int d = 0; d < 8; ++d) {
            h3[n * 8 + d] = acc[d];
            l += acc[d] * al[d];
            r += acc[d] * ar[d];
        }
        el[n] = l;
        er[n] = r;
    }
}

// ---------------- layer 3 softmax + aggregate (H=1, D=8) -------------------
// Round-3 proven two-pass version.
__global__ __launch_bounds__(256)
void gat_agg3(const float* __restrict__ h3, const float* __restrict__ el,
              const float* __restrict__ er, const int* __restrict__ row_ptr,
              const int* __restrict__ csr_src, const float* __restrict__ bias,
              float* __restrict__ out, int N) {
    int tid = threadIdx.x;
    int lane = tid & 63;
    int n = blockIdx.x * 4 + (tid >> 6);
    if (n >= N) return;
    int beg = row_ptr[n], end = row_ptr[n + 1];
    float er_n = er[n];
    float mx = -INFINITY;
    for (int j = beg + lane; j < end; j += 64) {
        float e = leaky02(el[csr_src[j]] + er_n);
        mx = fmaxf(mx, e);
    }
    #pragma unroll
    for (int o = 1; o < 64; o <<= 1) mx = fmaxf(mx, __shfl_xor(mx, o));
    float sm = 0.f;
    for (int j = beg + lane; j < end; j += 64) {
        float e = leaky02(el[csr_src[j]] + er_n);
        sm += __expf(e - mx);
    }
    #pragma unroll
    for (int o = 1; o < 64; o <<= 1) sm += __shfl_xor(sm, o);
    float inv = sm > 0.f ? 1.0f / sm : 0.0f;
    int g = lane >> 3, c = lane & 7;
    float acc = 0.f;
    for (int j = beg + g; j < end; j += 8) {
        int s = csr_src[j];
        float a = __expf(leaky02(el[s] + er_n) - mx) * inv;
        acc += h3[s * 8 + c] * a;
    }
    acc += __shfl_xor(acc, 8);
    acc += __shfl_xor(acc, 16);
    acc += __shfl_xor(acc, 32);
    if (lane < 8) out[(size_t)n * 8 + lane] = acc + bias[lane];
}

// ---------------------------------------------------------------------------
static inline size_t align_up(size_t x, size_t a) { return (x + a - 1) & ~(a - 1); }

extern "C" void kernel_launch(void* const* d_in, const int* in_sizes, int n_in,
                              void* d_out, int out_size, void* d_ws, size_t ws_size,
                              hipStream_t stream) {
    const float* feat = (const float*)d_in[0];
    const int*   src  = (const int*)d_in[1];
    const int*   dst  = (const int*)d_in[2];
    const float* W1   = (const float*)d_in[3];
    const float* al1  = (const float*)d_in[4];
    const float* ar1  = (const float*)d_in[5];
    const float* b1   = (const float*)d_in[6];
    const float* W2   = (const float*)d_in[7];
    const float* al2  = (const float*)d_in[8];
    const float* ar2  = (const float*)d_in[9];
    const float* b2   = (const float*)d_in[10];
    const float* W3   = (const float*)d_in[11];
    const float* al3  = (const float*)d_in[12];
    const float* ar3  = (const float*)d_in[13];
    const float* b3   = (const float*)d_in[14];

    const int N = in_sizes[0] / 128;
    const int E = in_sizes[1];

    char* w = (char*)d_ws;
    _Float16* bufA16 = (_Float16*)w; w += align_up((size_t)N * 256 * 2, 256);
    _Float16* bufB16 = (_Float16*)w; w += align_up((size_t)N * 256 * 2, 256);
    _Float16* W1T    = (_Float16*)w; w += align_up((size_t)256 * 128 * 2, 256);
    _Float16* W2T    = (_Float16*)w; w += align_up((size_t)256 * 256 * 2, 256);
    float* el      = (float*)w; w += align_up((size_t)N * 4 * 4, 256);
    float* er      = (float*)w; w += align_up((size_t)N * 4 * 4, 256);
    float* h3      = (float*)w; w += align_up((size_t)N * 8 * 4, 256);
    int*   cnt     = (int*)w;   w += align_up((size_t)N * 4, 256);
    int*   incl    = (int*)w;   w += align_up((size_t)N * 4, 256);
    int*   bsum    = (int*)w;   w += align_up(256 * 4, 256);
    int*   row_ptr = (int*)w;   w += align_up(((size_t)N + 1) * 4, 256);
    int*   nxt     = (int*)w;   w += align_up((size_t)N * 4, 256);
    int*   csr_src = (int*)w;   w += align_up((size_t)E * 4, 256);
    (void)ws_size; (void)n_in; (void)out_size;

    const int G1 = (N + 255) / 256;
    const int GE = (E + 255) / 256;

    // ---- CSR build (dst identical for all layers) ----
    hipMemsetAsync(cnt, 0, (size_t)N * 4, stream);
    count_edges<<<GE, 256, 0, stream>>>(dst, cnt, E);
    scan_block<<<G1, 256, 0, stream>>>(cnt, incl, bsum, N);
    scan_sums<<<1, 256, 0, stream>>>(bsum, G1);
    finalize_rowptr<<<G1, 256, 0, stream>>>(incl, cnt, bsum, row_ptr, nxt, N, E);
    fill_csr<<<GE, 256, 0, stream>>>(src, dst, nxt, csr_src, E);

    // ---- weight prep (single dispatch) ----
    transpose_w2<<<(128 * 256 + 256 * 256 + 255) / 256, 256, 0, stream>>>(W1, W1T, W2, W2T);

    dim3 ggrid(2, (N + GBM - 1) / GBM);
    const int GA = (N + 7) / 8;
    const int GL = (N * 4 + 31) / 32;   // attn_lr: 32 rows per block

    // ---- layer 1 ----
    gemm_mfma<true><<<ggrid, 256, 0, stream>>>(feat, W1T, bufA16, N, 128);
    attn_lr<<<GL, 256, 0, stream>>>(bufA16, al1, ar1, el, er, N * 4);
    gat_agg<<<GA, 256, 0, stream>>>(bufA16, el, er, row_ptr, csr_src, b1, bufB16, N);

    // ---- layer 2 ----
    gemm_mfma<false><<<ggrid, 256, 0, stream>>>(bufB16, W2T, bufA16, N, 256);
    attn_lr<<<GL, 256, 0, stream>>>(bufA16, al2, ar2, el, er, N * 4);
    gat_agg<<<GA, 256, 0, stream>>>(bufA16, el, er, row_ptr, csr_src, b2, bufB16, N);

    // ---- layer 3 ----
    gemm3_attn<<<(N + 3) / 4, 256, 0, stream>>>(bufB16, W3, al3, ar3, h3, el, er, N);
    gat_agg3<<<(N + 3) / 4, 256, 0, stream>>>(h3, el, er, row_ptr, csr_src, b3,
                                              (float*)d_out, N);
}